// Round 8
// baseline (73.233 us; speedup 1.0000x reference)
//
#include <hip/hip_runtime.h>
#include <hip/hip_bf16.h>

// LearnedQueryAttention — v8: GEMM-first restructure.
//  * Q=1 broadcast query => one score per (b,h,key): s = x.c_h (c folded
//    from qb,w_q,w_k incl. 1/8).
//  * complement-mask softmax => pooled = (N_all - N_seg)/(D_all - D_seg).
//  * NEW: v = x @ B_aug^T where B_aug = [w_v (512 rows) | c (8) | 0 (56)]:
//    one clean 16384x576x512 bf16 MFMA GEMM produces v AND scores->E=exp(s).
//    Then N_seg[l,j] = sum_{k in seg l} e_{h(j)}(k) * v[k,j] is a barrier-free
//    streaming reduction (no LDS, no chunk staging — R4's k_pseg at ~25us and
//    R7's fused psegv at ~62us were both latency-bound on that machinery).
//  * N_all accumulated via per-block atomics in k_nseg; gemm_o R4-verbatim.
// Shapes: B=4 S=4096 D=512 H=8 SEG=L=256.

#define S 4096
#define D 512
#define H 8
#define SEG 256

typedef short bf16x8 __attribute__((ext_vector_type(8)));
typedef float fvec4  __attribute__((ext_vector_type(4)));

// workspace layout (float offsets)
constexpr int    OFF_SEGO   = 0;          // [4][257] ints (+pad)
constexpr int    OFF_DSEG   = 1032;       // [1024][8] f32
constexpr int    OFF_NALL   = 9224;       // [4][512] f32
constexpr int    OFF_E_F    = 11272;      // E [16384][8] bf16   = 65536 f32
constexpr int    OFF_V_F    = 76808;      // v [16384][512] bf16 = 4194304 f32
constexpr int    OFF_NSEG_F = 4271112;    // N_seg [1024][512] bf16 = 262144 f32
constexpr int    OFF_BAUG_F = 4533256;    // B_aug [576][512] bf16 = 147456 f32
constexpr size_t WS_FLOATS  = 4680712;    // ~18.7 MB

static __device__ inline ushort f2bf(float f) {
    __hip_bfloat16 h = __float2bfloat16(f);
    return *reinterpret_cast<ushort*>(&h);
}
static __device__ inline float bf2f(ushort u) {
    return __uint_as_float(((uint)u) << 16);
}
static __device__ inline uint pack2(float a, float b) {
    return (uint)f2bf(a) | ((uint)f2bf(b) << 16);
}

// ---- K1: c->B_aug rows 512-519 (blk 0-7), sego (8-11), zero NALL + B_aug
//          pad rows (12), w_v->bf16 into B_aug rows 0-511 (13-44)
__global__ __launch_bounds__(512) void k_setup(const float* __restrict__ qb,
        const float* __restrict__ w_q, const float* __restrict__ w_k,
        const float* __restrict__ w_v, const int* __restrict__ seg_id,
        float* __restrict__ W) {
    int tid = threadIdx.x, blk = blockIdx.x;
    ushort* baug = (ushort*)(W + OFF_BAUG_F);
    if (blk < 8) {
        __shared__ float qbs[D];
        __shared__ float part[64][9];
        __shared__ float qp[64];
        int h = blk;
        qbs[tid] = qb[tid];
        __syncthreads();
        int jj = tid >> 3, p = tid & 7;
        const float* wr = w_q + (size_t)(h*64 + jj)*D;
        float a = 0.f;
        for (int t = 0; t < 64; ++t) a += qbs[p + 8*t] * wr[p + 8*t];
        part[jj][p] = a;
        __syncthreads();
        if (tid < 64) {
            float s = 0.f;
            #pragma unroll
            for (int p2 = 0; p2 < 8; ++p2) s += part[tid][p2];
            qp[tid] = s;
        }
        __syncthreads();
        float c = 0.f;
        for (int j2 = 0; j2 < 64; ++j2)
            c += qp[j2] * w_k[(size_t)(h*64 + j2)*D + tid];
        baug[(size_t)(512 + h)*512 + tid] = f2bf(c * 0.125f);
    } else if (blk < 12) {
        int b = blk - 8;
        if (tid <= SEG) {
            const int* sid = seg_id + (size_t)b*S;
            int lo = 0, hi = S;
            while (lo < hi) { int mid = (lo+hi) >> 1; if (sid[mid] < tid) lo = mid+1; else hi = mid; }
            ((int*)(W + OFF_SEGO))[b*(SEG+1) + tid] = lo;
        }
    } else if (blk == 12) {
        for (int t = tid; t < 4*D; t += 512) W[OFF_NALL + t] = 0.f;
        // zero B_aug rows 520..575 (56*512 u16 = 14336 uints, base u16 520*512)
        uint* pB = (uint*)baug;
        for (int t = tid; t < 14336; t += 512) pB[133120 + t] = 0u;
    } else {
        // w_v -> bf16 rows 0..511 (32 blocks x 8192 elems)
        int base = (blk - 13) * 8192;
        #pragma unroll
        for (int rep = 0; rep < 2; ++rep) {
            int idx = base + rep*4096 + tid*8;
            const float4* s4 = (const float4*)(w_v + idx);
            float4 v0 = s4[0], v1 = s4[1];
            uint4 u;
            u.x = pack2(v0.x, v0.y); u.y = pack2(v0.z, v0.w);
            u.z = pack2(v1.x, v1.y); u.w = pack2(v1.z, v1.w);
            *(uint4*)&baug[idx] = u;
        }
    }
}

// ---- K2: v_aug = x @ B_aug^T. Grid (512 rt x 32 rows, 9 nt x 64 cols).
//          nt<8: write v bf16. nt==8: cols 0-7 are scores -> E = exp bf16.
//          K-chunked BK=128, 32x64 tile, R4-proven fragment pattern.
__global__ __launch_bounds__(256) void k_ev(const float* __restrict__ x,
                                            float* __restrict__ W) {
    __shared__ ushort As[32][136];
    __shared__ ushort Bs[64][136];
    int rt = blockIdx.x, nt = blockIdx.y, tid = threadIdx.x;
    const ushort* baug = (const ushort*)(W + OFF_BAUG_F);
    int lane = tid & 63, w = tid >> 6;
    int wm = w & 1, wn = w >> 1;
    int m = lane & 15, kg = lane >> 4;
    fvec4 acc0 = {0,0,0,0}, acc1 = {0,0,0,0};
    for (int kc = 0; kc < 4; ++kc) {
        __syncthreads();
        #pragma unroll
        for (int rep = 0; rep < 4; ++rep) {           // A: 32x128 f32 -> bf16
            int idx = rep*256 + tid, r = idx >> 5, c4 = idx & 31;
            float4 v = *(const float4*)(x + (size_t)(rt*32 + r)*512 + kc*128 + c4*4);
            uint2 u; u.x = pack2(v.x, v.y); u.y = pack2(v.z, v.w);
            *(uint2*)&As[r][c4*4] = u;
        }
        #pragma unroll
        for (int rep = 0; rep < 4; ++rep) {           // B: 64x128 bf16
            int idx = rep*256 + tid, r = idx >> 4, c8 = idx & 15;
            *(bf16x8*)&Bs[r][c8*8] =
                *(const bf16x8*)&baug[(size_t)(nt*64 + r)*512 + kc*128 + c8*8];
        }
        __syncthreads();
        #pragma unroll
        for (int ks = 0; ks < 128; ks += 32) {
            bf16x8 a  = *(const bf16x8*)&As[wm*16 + m][ks + kg*8];
            bf16x8 b0 = *(const bf16x8*)&Bs[wn*32 + m][ks + kg*8];
            bf16x8 b1 = *(const bf16x8*)&Bs[wn*32 + 16 + m][ks + kg*8];
            acc0 = __builtin_amdgcn_mfma_f32_16x16x32_bf16(a, b0, acc0, 0, 0, 0);
            acc1 = __builtin_amdgcn_mfma_f32_16x16x32_bf16(a, b1, acc1, 0, 0, 0);
        }
    }
    int rowb = rt*32 + wm*16 + kg*4;
    if (nt < 8) {
        ushort* vb = (ushort*)(W + OFF_V_F);
        int col0 = nt*64 + wn*32 + m, col1 = col0 + 16;
        #pragma unroll
        for (int r = 0; r < 4; ++r) {
            vb[(size_t)(rowb + r)*512 + col0] = f2bf(acc0[r]);
            vb[(size_t)(rowb + r)*512 + col1] = f2bf(acc1[r]);
        }
    } else if (wn == 0 && m < 8) {                    // score cols 0-7 of tile
        ushort* Eb = (ushort*)(W + OFF_E_F);
        #pragma unroll
        for (int r = 0; r < 4; ++r)
            Eb[(size_t)(rowb + r)*8 + m] = f2bf(__expf(acc0[r]));
    }
}

// ---- K3: barrier-free segmented reduction. 1024 blocks (1 segment each).
//          thread owns cols j=2*tid,2*tid+1 (same head h=tid>>5).
//          N_seg bf16 + D_seg + atomicAdd N_all.
__global__ __launch_bounds__(256) void k_nseg(float* __restrict__ W) {
    int row = blockIdx.x, b = row >> 8, l = row & 255, tid = threadIdx.x;
    const int* offp = (const int*)(W + OFF_SEGO);
    int k0 = __builtin_amdgcn_readfirstlane(offp[b*257 + l]);
    int k1 = __builtin_amdgcn_readfirstlane(offp[b*257 + l + 1]);
    const ushort* vb = (const ushort*)(W + OFF_V_F);
    const ushort* Eb = (const ushort*)(W + OFF_E_F);
    int h = tid >> 5;
    float acc0 = 0.f, acc1 = 0.f, es = 0.f;
    for (int k = k0; k < k1; ++k) {
        size_t key = (size_t)(b*S + k);
        float e = bf2f(Eb[key*8 + h]);
        uint vv = *(const uint*)&vb[key*512 + 2*tid];
        acc0 += e * bf2f((ushort)(vv & 0xffff));
        acc1 += e * bf2f((ushort)(vv >> 16));
        es   += e;
    }
    ushort* NSb = (ushort*)(W + OFF_NSEG_F);
    *(uint*)&NSb[(size_t)row*512 + 2*tid] = pack2(acc0, acc1);
    atomicAdd(&W[OFF_NALL + b*512 + 2*tid],     acc0);
    atomicAdd(&W[OFF_NALL + b*512 + 2*tid + 1], acc1);
    if ((tid & 31) == 0) W[OFF_DSEG + row*8 + h] = es;
}

// ---- K4: out = pooled @ w_o^T via MFMA; pooled built in A-staging (R4-proven)
__global__ __launch_bounds__(256) void k_gemm_o(const float* __restrict__ w_o,
                                                float* __restrict__ W,
                                                float* __restrict__ out) {
    __shared__ ushort As[32][520];
    __shared__ ushort Bs[64][520];
    __shared__ float NAl[512];
    __shared__ float dpart[8][8];
    __shared__ float invs[32][8];
    int rt = blockIdx.x, nt = blockIdx.y, tid = threadIdx.x;
    int b = rt >> 3;
    if (tid < 64) {
        int h = tid >> 3, sg = tid & 7;
        float s = 0.f;
        for (int l2 = sg*32; l2 < sg*32 + 32; ++l2)
            s += W[OFF_DSEG + (b*256 + l2)*8 + h];
        dpart[h][sg] = s;
    }
    NAl[tid]       = W[OFF_NALL + b*512 + tid];
    NAl[tid + 256] = W[OFF_NALL + b*512 + tid + 256];
    __syncthreads();
    {
        int r = tid >> 3, h = tid & 7;
        float da = 0.f;
        #pragma unroll
        for (int sg = 0; sg < 8; ++sg) da += dpart[h][sg];
        invs[r][h] = 1.f / (da - W[OFF_DSEG + (rt*32 + r)*8 + h]);
    }
    #pragma unroll
    for (int rep = 0; rep < 32; ++rep) {
        int idx = rep*256 + tid, r = idx >> 7, c4 = idx & 127;
        float4 v = ((const float4*)(w_o + (size_t)(nt*64 + r)*512))[c4];
        uint2 u; u.x = pack2(v.x, v.y); u.y = pack2(v.z, v.w);
        *(uint2*)&Bs[r][c4*4] = u;
    }
    __syncthreads();
    const ushort* NSb = (const ushort*)(W + OFF_NSEG_F);
    #pragma unroll
    for (int rep = 0; rep < 8; ++rep) {
        int idx = rep*256 + tid, r = idx >> 6, j = idx & 63;
        bf16x8 ns = *(const bf16x8*)&NSb[(size_t)(rt*32 + r)*512 + j*8];
        float inv = invs[r][j >> 3];
        ushort o[8];
        #pragma unroll
        for (int e = 0; e < 8; ++e)
            o[e] = f2bf((NAl[j*8 + e] - bf2f((ushort)ns[e])) * inv);
        uint4 u;
        u.x = o[0] | ((uint)o[1] << 16);
        u.y = o[2] | ((uint)o[3] << 16);
        u.z = o[4] | ((uint)o[5] << 16);
        u.w = o[6] | ((uint)o[7] << 16);
        *(uint4*)&As[r][j*8] = u;
    }
    __syncthreads();
    int lane = tid & 63, w = tid >> 6;
    int wm = w & 1, wn = w >> 1;
    int m = lane & 15, kg = lane >> 4;
    fvec4 acc0 = {0,0,0,0}, acc1 = {0,0,0,0};
    for (int ks = 0; ks < 512; ks += 32) {
        bf16x8 a  = *(const bf16x8*)&As[wm*16 + m][ks + kg*8];
        bf16x8 b0 = *(const bf16x8*)&Bs[wn*32 + m][ks + kg*8];
        bf16x8 b1 = *(const bf16x8*)&Bs[wn*32 + 16 + m][ks + kg*8];
        acc0 = __builtin_amdgcn_mfma_f32_16x16x32_bf16(a, b0, acc0, 0, 0, 0);
        acc1 = __builtin_amdgcn_mfma_f32_16x16x32_bf16(a, b1, acc1, 0, 0, 0);
    }
    int rowb = rt*32 + wm*16 + kg*4;
    int col0 = nt*64 + wn*32 + m, col1 = col0 + 16;
    #pragma unroll
    for (int r = 0; r < 4; ++r) {
        out[(size_t)(rowb + r)*512 + col0] = acc0[r];
        out[(size_t)(rowb + r)*512 + col1] = acc1[r];
    }
}

extern "C" void kernel_launch(void* const* d_in, const int* in_sizes, int n_in,
                              void* d_out, int out_size, void* d_ws, size_t ws_size,
                              hipStream_t stream) {
    const float* x   = (const float*)d_in[0];
    const int*   seg = (const int*)d_in[1];
    // d_in[2] = valid_mask (all True), d_in[3] = s_seg_max (=256) — unused
    const float* qb  = (const float*)d_in[4];
    const float* w_q = (const float*)d_in[5];
    const float* w_k = (const float*)d_in[6];
    const float* w_v = (const float*)d_in[7];
    const float* w_o = (const float*)d_in[8];
    float* W   = (float*)d_ws;
    float* out = (float*)d_out;

    if (ws_size < WS_FLOATS * sizeof(float)) return;

    hipLaunchKernelGGL(k_setup,  dim3(45),     dim3(512), 0, stream, qb, w_q, w_k, w_v, seg, W);
    hipLaunchKernelGGL(k_ev,     dim3(512, 9), dim3(256), 0, stream, x, W);
    hipLaunchKernelGGL(k_nseg,   dim3(1024),   dim3(256), 0, stream, W);
    hipLaunchKernelGGL(k_gemm_o, dim3(32, 8),  dim3(256), 0, stream, w_o, W, out);
}